// Round 12
// baseline (32.274 us; speedup 1.0000x reference)
//
#include <hip/hip_runtime.h>

// CTC batch cost, forward-backward split, f64 probability domain with
// wave-uniform power-of-2 renorm per 32-step group (exact; integer c).
// Round-12 change vs round-11: GROUP-GRANULAR register double-buffering.
// 32 loads burst-issued into buffer B while computing from buffer A (all
// statically indexed), one counted vmcnt wait per group instead of the
// per-step rolling prefetch window the compiler degrades to vmcnt(0).
// Wave 0: forward alpha_255 (t=0..255). Wave 1: backward beta_255 (t=511..256).
// loglik = log2(sum_s alpha_255[s]*beta_255[s]*2^(ca+cb)).
// Lane l holds extended states {2l, 2l+1}; S=97 -> lanes 0..48 live.

constexpr int Bc = 512, Tc = 512, Cc = 128, Lc = 48;
constexpr double DEPS = 1e-7;
constexpr float FNEG = -1e30f;
constexpr float LN2F = 0.69314718055994530942f;

#define DPP_WAVE_SHR1 0x138
#define DPP_WAVE_SHL1 0x130

__device__ __forceinline__ double dpp64_shr1(double x) {
    // lane l <- lane l-1; lane 0 <- 0.0
    long long u = __double_as_longlong(x);
    int a = __builtin_amdgcn_update_dpp(0, (int)u,         DPP_WAVE_SHR1, 0xF, 0xF, false);
    int b = __builtin_amdgcn_update_dpp(0, (int)(u >> 32), DPP_WAVE_SHR1, 0xF, 0xF, false);
    return __longlong_as_double(((long long)b << 32) | (unsigned int)a);
}
__device__ __forceinline__ double dpp64_shl1(double x) {
    // lane l <- lane l+1; lane 63 <- 0.0
    long long u = __double_as_longlong(x);
    int a = __builtin_amdgcn_update_dpp(0, (int)u,         DPP_WAVE_SHL1, 0xF, 0xF, false);
    int b = __builtin_amdgcn_update_dpp(0, (int)(u >> 32), DPP_WAVE_SHL1, 0xF, 0xF, false);
    return __longlong_as_double(((long long)b << 32) | (unsigned int)a);
}

__device__ __forceinline__ float lae2(float a, float b) {  // final reduce only
    float m = fmaxf(a, b);
    float d = fabsf(a - b);
    return m + __log2f(1.0f + __builtin_amdgcn_exp2f(-d));
}
__device__ __forceinline__ float blankpf(float praw) {
    return __uint_as_float((unsigned)
        __builtin_amdgcn_readlane(__float_as_uint(praw), 63));
}
__device__ __forceinline__ float log2d(double x) {
    // log2 of a positive normal f64; zero/denormal -> log-zero
    if (!(x > 0.0)) return FNEG;
    long long u = __double_as_longlong(x);
    int e = (int)((u >> 52) & 0x7FF);
    if (e == 0) return FNEG;
    double m = __longlong_as_double((u & 0x000FFFFFFFFFFFFFLL) | 0x3FF0000000000000LL);
    return __log2f((float)m) + (float)(e - 1023);
}

__global__ __launch_bounds__(128)
void ctc_fb_kernel(const int* __restrict__ y_true,
                   const float* __restrict__ y_pred,
                   float* __restrict__ out) {
    const int b = blockIdx.x;
    const int lane = threadIdx.x & 63;
    const int wave = threadIdx.x >> 6;

    const float* yb = y_pred + (size_t)b * Tc * Cc;

    const int lab = (lane < Lc) ? y_true[b * Lc + lane] : (Cc - 1);
    const int labm1 = __builtin_amdgcn_ds_bpermute(((lane + 63) & 63) << 2, lab);
    const int labp1 = __builtin_amdgcn_ds_bpermute(((lane + 1) & 63) << 2, lab);
    const bool skip  = (lab != (Cc - 1)) && (lab != labm1);   // into 2l+1 from 2l-1
    const bool skipN = (labp1 != (Cc - 1)) && (labp1 != lab); // out of 2l+1 into 2l+3
    const bool validhi = (lane < Lc);
    const bool lane0 = (lane == 0);

    __shared__ double sblo[64], sbhi[64];
    __shared__ int sbc[64];

    double lo = 0.0, hi = 0.0;
    int c = 0;   // wave-uniform log2 scale (exact integer)

    auto renorm = [&]() {   // once per 32-step group
        double mx = fmax(lo, hi);
        #pragma unroll
        for (int mk = 1; mk < 64; mk <<= 1)
            mx = fmax(mx, __shfl_xor(mx, mk, 64));
        int e = (int)((__double_as_longlong(mx) >> 52) & 0x7FF) - 1023;
        double sc = __longlong_as_double((long long)(1023 - e) << 52);  // exact 2^-e
        lo *= sc; hi *= sc;
        c += e;
    };

    float A[32], B[32];

    if (wave == 0) {
        // -------- forward: alpha_255, consume p_0..p_255 --------
        auto dostep = [&](float praw) {
            double pb = (double)blankpf(praw) + DEPS;
            double ph = validhi ? ((double)praw + DEPS) : 0.0;
            double sh = dpp64_shr1(hi);        // alpha[2l-1]
            double a3 = skip ? sh : 0.0;
            double nlo = (lo + sh) * pb;       // even state (blank)
            double nhi = (hi + lo + a3) * ph;  // odd state (label)
            lo = nlo; hi = nhi;
        };
        auto issue = [&](float (&buf)[32], int g) {   // burst: 32 loads, group g
            const float* p = yb + (size_t)g * 32 * Cc + lab;
            #pragma unroll
            for (int j = 0; j < 32; ++j) buf[j] = p[(size_t)j * Cc];
        };
        auto compute = [&](float (&buf)[32]) {
            #pragma unroll
            for (int j = 0; j < 32; ++j) dostep(buf[j]);
            renorm();
        };
        issue(A, 0);
        issue(B, 1);
        {   // group 0 (A) with t=0 init
            float praw = A[0];
            lo = lane0 ? ((double)blankpf(praw) + DEPS) : 0.0;  // state 0 = blank
            hi = lane0 ? ((double)praw + DEPS) : 0.0;           // state 1 = label[0]
            #pragma unroll
            for (int j = 1; j < 32; ++j) dostep(A[j]);
            renorm();
        }
        issue(A, 2);
        compute(B); issue(B, 3);
        #pragma unroll 1
        for (int g = 2; g <= 4; g += 2) {
            compute(A); issue(A, g + 2);
            compute(B); issue(B, g + 3);
        }
        compute(A);   // group 6
        compute(B);   // group 7
    } else {
        // -------- backward: beta_255, consume p_511..p_256 --------
        // q[s] = beta_{t+1}[s] * p_{t+1}[s]
        // beta_t[2l]   = q[2l] + q[2l+1]
        // beta_t[2l+1] = q[2l+1] + q[2l+2] + (skipN ? q[2l+3] : 0)
        auto dostep = [&](float praw) {
            double pb = (double)blankpf(praw) + DEPS;
            double ph = validhi ? ((double)praw + DEPS) : 0.0;
            double qlo = lo * pb;              // q[2l]
            double qhi = hi * ph;              // q[2l+1]
            double qlo_n = dpp64_shl1(qlo);    // q[2l+2]
            double qhi_n = dpp64_shl1(qhi);    // q[2l+3]
            double nb = skipN ? (qlo_n + qhi_n) : qlo_n;
            lo = qlo + qhi;
            hi = qhi + nb;
        };
        auto issue = [&](float (&buf)[32], int g) {   // t = 511 - (g*32+j)
            const float* p = yb + (size_t)(511 - g * 32) * Cc + lab;
            #pragma unroll
            for (int j = 0; j < 32; ++j) buf[j] = p[-(ptrdiff_t)j * Cc];
        };
        auto compute = [&](float (&buf)[32]) {
            #pragma unroll
            for (int j = 0; j < 32; ++j) dostep(buf[j]);
            renorm();
        };
        // init beta_511: state 96 (lane48.lo) = 1, state 95 (lane47.hi) = 1
        lo = (lane == 48) ? 1.0 : 0.0;
        hi = (lane == 47) ? 1.0 : 0.0;
        issue(A, 0);
        issue(B, 1);
        compute(A); issue(A, 2);
        compute(B); issue(B, 3);
        #pragma unroll 1
        for (int g = 2; g <= 4; g += 2) {
            compute(A); issue(A, g + 2);
            compute(B); issue(B, g + 3);
        }
        compute(A);   // group 6
        compute(B);   // group 7
        sblo[lane] = lo;
        sbhi[lane] = hi;
        sbc[lane]  = c;
    }

    __syncthreads();

    if (wave == 0) {
        // loglik = log2( sum_s alpha_255[s]*beta_255[s] ) + ca + cb
        double plo = lo * sblo[lane];
        double phi = hi * sbhi[lane];
        float ctot = (float)(c + sbc[lane]);
        float yl = log2d(plo) + ctot;
        float yh = log2d(phi) + ctot;
        float v = lae2(yl, yh);
        #pragma unroll
        for (int mk = 1; mk < 64; mk <<= 1)
            v = lae2(v, __shfl_xor(v, mk, 64));
        if (lane0) out[b] = -(v * LN2F);
    }
}

extern "C" void kernel_launch(void* const* d_in, const int* in_sizes, int n_in,
                              void* d_out, int out_size, void* d_ws, size_t ws_size,
                              hipStream_t stream) {
    const int* y_true = (const int*)d_in[0];
    const float* y_pred = (const float*)d_in[1];
    float* out = (float*)d_out;
    hipLaunchKernelGGL(ctc_fb_kernel, dim3(Bc), dim3(128), 0, stream,
                       y_true, y_pred, out);
}

// Round 13
// 31.384 us; speedup vs baseline: 1.0284x; 1.0284x over previous
//
#include <hip/hip_runtime.h>

// CTC batch cost, forward-backward split, f64 probability domain, wave-uniform
// power-of-2 renorm per 32-step group (exact; integer c).
// Round-13 restructure: staging via global_load_lds (coalesced, async, no dest
// VGPRs) -> LDS row buffer -> batched ds_read_b32 gather into praw[32] regs.
// One vmcnt drain per group (hidden under the previous group's compute).
// Dead-lane selects removed from the chain: junk is confined (fwd) or
// firewalled by zeroing praw@lane48 off-chain (bwd); final combine masks.
// Wave 0: forward alpha_255 (t=0..255). Wave 1: backward beta_255 (t=511..256).
// loglik = log2(sum_s alpha_255[s]*beta_255[s]*2^(ca+cb)).

constexpr int Bc = 512, Tc = 512, Cc = 128, Lc = 48;
constexpr float FEPS = 1e-7f;
constexpr float FNEG = -1e30f;
constexpr float LN2F = 0.69314718055994530942f;

#define DPP_WAVE_SHR1 0x138
#define DPP_WAVE_SHL1 0x130

__device__ __forceinline__ double dpp64_shr1(double x) {
    long long u = __double_as_longlong(x);
    int a = __builtin_amdgcn_update_dpp(0, (int)u,         DPP_WAVE_SHR1, 0xF, 0xF, false);
    int b = __builtin_amdgcn_update_dpp(0, (int)(u >> 32), DPP_WAVE_SHR1, 0xF, 0xF, false);
    return __longlong_as_double(((long long)b << 32) | (unsigned int)a);
}
__device__ __forceinline__ double dpp64_shl1(double x) {
    long long u = __double_as_longlong(x);
    int a = __builtin_amdgcn_update_dpp(0, (int)u,         DPP_WAVE_SHL1, 0xF, 0xF, false);
    int b = __builtin_amdgcn_update_dpp(0, (int)(u >> 32), DPP_WAVE_SHL1, 0xF, 0xF, false);
    return __longlong_as_double(((long long)b << 32) | (unsigned int)a);
}

__device__ __forceinline__ float lae2(float a, float b) {  // final reduce only
    float m = fmaxf(a, b);
    float d = fabsf(a - b);
    return m + __log2f(1.0f + __builtin_amdgcn_exp2f(-d));
}
__device__ __forceinline__ float log2d(double x) {
    if (!(x > 0.0)) return FNEG;
    long long u = __double_as_longlong(x);
    int e = (int)((u >> 52) & 0x7FF);
    if (e == 0) return FNEG;
    double m = __longlong_as_double((u & 0x000FFFFFFFFFFFFFLL) | 0x3FF0000000000000LL);
    return __log2f((float)m) + (float)(e - 1023);
}
__device__ __forceinline__ float rdlane63(float v) {
    return __uint_as_float((unsigned)__builtin_amdgcn_readlane(__float_as_uint(v), 63));
}

typedef const __attribute__((address_space(1))) void* gptr_t;
typedef __attribute__((address_space(3))) void* lptr_t;
__device__ __forceinline__ void gload(const float* g, float* l) {
    __builtin_amdgcn_global_load_lds((gptr_t)g, (lptr_t)l, 4, 0, 0);
}

__global__ __launch_bounds__(128)
void ctc_fb_kernel(const int* __restrict__ y_true,
                   const float* __restrict__ y_pred,
                   float* __restrict__ out) {
    __shared__ float rowbuf[2][2][32][Cc];   // [wave][pingpong][row][class] = 64 KB
    __shared__ double sblo[64], sbhi[64];
    __shared__ int sbc[64];

    const int b = blockIdx.x;
    const int lane = threadIdx.x & 63;
    const int wave = threadIdx.x >> 6;
    const float* yb = y_pred + (size_t)b * Tc * Cc;

    const int lab = (lane < Lc) ? y_true[b * Lc + lane] : (Cc - 1);
    const int labm1 = __builtin_amdgcn_ds_bpermute(((lane + 63) & 63) << 2, lab);
    const int labp1 = __builtin_amdgcn_ds_bpermute(((lane + 1) & 63) << 2, lab);
    const bool skip  = (lab != (Cc - 1)) && (lab != labm1);   // into 2l+1 from 2l-1
    const bool skipN = (labp1 != (Cc - 1)) && (labp1 != lab); // out of 2l+1 into 2l+3
    const bool lane0 = (lane == 0);

    float (*buf)[32][Cc] = rowbuf[wave];
    // unified row addressing: fwd row k is t=k; bwd row k is t=511-k  (k = 32g+j)
    const ptrdiff_t rs = wave ? -(ptrdiff_t)Cc : (ptrdiff_t)Cc;
    const float* g0 = yb + (wave ? (size_t)(Tc - 1) * Cc : 0) + lane;

    auto stage = [&](int pg, int g) {   // async: 32 rows -> buf[pg], no dest VGPRs
        const float* gb = g0 + (ptrdiff_t)(g * 32) * rs;
        float* lb = &buf[pg][0][0];
        #pragma unroll
        for (int j = 0; j < 32; ++j) {
            const float* gr = gb + (ptrdiff_t)j * rs;
            gload(gr, lb + j * Cc);
            gload(gr + 64, lb + j * Cc + 64);
        }
    };

    double lo = 0.0, hi = 0.0;
    int c = 0;   // wave-uniform log2 scale (exact integer)

    auto renorm = [&]() {
        double mx = fmax(lo, hi);
        #pragma unroll
        for (int mk = 1; mk < 64; mk <<= 1)
            mx = fmax(mx, __shfl_xor(mx, mk, 64));
        int e = (int)((__double_as_longlong(mx) >> 52) & 0x7FF) - 1023;
        double sc = __longlong_as_double((long long)(1023 - e) << 52);  // exact 2^-e
        lo *= sc; hi *= sc;
        c += e;
    };

    float praw[32];
    auto readgrp = [&](int pg) {   // batched LDS gather (compiler: one vmcnt, counted lgkm)
        #pragma unroll
        for (int j = 0; j < 32; ++j) praw[j] = buf[pg][j][lab];
        // ensure ds_reads complete before this buffer is restaged (WAR fence)
        asm volatile("s_waitcnt lgkmcnt(0)" ::: "memory");
    };

    auto fstep = [&](float pr) {
        float pe = pr + FEPS;
        double ph = (double)pe;
        double pb = (double)rdlane63(pe);
        double sh = dpp64_shr1(hi);        // alpha[2l-1]
        double a3 = skip ? sh : 0.0;
        double nlo = (lo + sh) * pb;       // even state (blank)
        double nhi = (hi + lo + a3) * ph;  // odd state (label)
        lo = nlo; hi = nhi;
    };
    auto bstep = [&](float pr) {
        float pe = (lane == 48) ? 0.0f : pr + FEPS;  // firewall: state-97 flux = 0
        double ph = (double)pe;
        double pb = (double)rdlane63(pr + FEPS);
        double qlo = lo * pb;              // q[2l]
        double qhi = hi * ph;              // q[2l+1]
        double qlo_n = dpp64_shl1(qlo);    // q[2l+2]
        double qhi_n = dpp64_shl1(qhi);    // q[2l+3]
        double nb = skipN ? (qlo_n + qhi_n) : qlo_n;
        lo = qlo + qhi;
        hi = qhi + nb;
    };

    stage(0, 0);
    stage(1, 1);

    // ---- group 0 ----
    readgrp(0);
    stage(0, 2);
    if (wave == 0) {
        float pe = praw[0] + FEPS;
        float pbf = rdlane63(pe);
        lo = lane0 ? (double)pbf : 0.0;   // state 0 = blank
        hi = lane0 ? (double)pe : 0.0;    // state 1 = label[0]
        #pragma unroll
        for (int j = 1; j < 32; ++j) fstep(praw[j]);
    } else {
        lo = (lane == 48) ? 1.0 : 0.0;    // beta_511: state 96
        hi = (lane == 47) ? 1.0 : 0.0;    // beta_511: state 95
        #pragma unroll
        for (int j = 0; j < 32; ++j) bstep(praw[j]);
    }
    renorm();

    // ---- groups 1..7 ----
    #pragma unroll 1
    for (int g = 1; g < 8; ++g) {
        const int pg = g & 1;
        readgrp(pg);
        if (g < 6) stage(pg, g + 2);
        if (wave == 0) {
            #pragma unroll
            for (int j = 0; j < 32; ++j) fstep(praw[j]);
        } else {
            #pragma unroll
            for (int j = 0; j < 32; ++j) bstep(praw[j]);
        }
        renorm();
    }

    if (wave == 1) {
        sblo[lane] = lo;
        sbhi[lane] = hi;
        sbc[lane]  = c;
    }
    __syncthreads();

    if (wave == 0) {
        // loglik = log2( sum_s alpha_255[s]*beta_255[s] ) + ca + cb
        // mask non-existent states (junk lanes): lo valid for lanes<=48 (s=2l<=96),
        // hi valid for lanes<=47 (s=2l+1<=95)
        double plo = (lane <= 48) ? lo * sblo[lane] : 0.0;
        double phi = (lane <= 47) ? hi * sbhi[lane] : 0.0;
        float ctot = (float)(c + sbc[lane]);
        float yl = log2d(plo) + ctot;
        float yh = log2d(phi) + ctot;
        float v = lae2(yl, yh);
        #pragma unroll
        for (int mk = 1; mk < 64; mk <<= 1)
            v = lae2(v, __shfl_xor(v, mk, 64));
        if (lane0) out[b] = -(v * LN2F);
    }
}

extern "C" void kernel_launch(void* const* d_in, const int* in_sizes, int n_in,
                              void* d_out, int out_size, void* d_ws, size_t ws_size,
                              hipStream_t stream) {
    const int* y_true = (const int*)d_in[0];
    const float* y_pred = (const float*)d_in[1];
    float* out = (float*)d_out;
    hipLaunchKernelGGL(ctc_fb_kernel, dim3(Bc), dim3(128), 0, stream,
                       y_true, y_pred, out);
}